// Round 16
// baseline (19.610 us; speedup 1.0000x reference)
//
#include <hip/hip_runtime.h>

typedef float    f32x4 __attribute__((ext_vector_type(4)));
typedef _Float16 h8    __attribute__((ext_vector_type(8)));
typedef unsigned u32x4 __attribute__((ext_vector_type(4)));

#define STRIP 16
#define SR 18          // site rows (strip + halo)
#define SC 66          // site cols (= stride)

__device__ __forceinline__ unsigned pkf16(float a, float b) {
    return __builtin_bit_cast(unsigned, __builtin_amdgcn_cvt_pkrtz(a, b));
}

// Block = 16-row strip of one (b,c) plane; 4 waves; LDS 23.8 KB; grid 1024 =
// 4 blocks/CU, one residency round.
// P1: per-site basis record via 128-bit shift placement (R15) + silu f32.
// P3: MFMA 16x16x32_f16, K=96: chunks 0-8 = spline taps (b0/b1/b2@cc0 from
//     shifted BSb reads), chunk 9 = base taps0-7 (cc==1 builds its B-fragment
//     INLINE from 9 Sil reads — P2 of earlier rounds deleted), chunk 10 =
//     base tap8 (cc==2, 1 Sil read), chunk 11 = zero.
//     C row = conv n, col = pixel [HW-verified R9].
__global__ __launch_bounds__(256, 4) void kan_conv_kernel(
    const float* __restrict__ x,     // (256, 64, 64)
    const float* __restrict__ bw,    // (8, 9)
    const float* __restrict__ sw,    // (8, 9, 8)
    const float* __restrict__ ss,    // (8, 9)
    float* __restrict__ out)         // (256, 8, 64, 64)
{
    __shared__ __align__(16) unsigned BSb[SR * SC * 4];   // 19,008 B
    __shared__ __align__(16) float    Sil[SR * SC];       //  4,752 B

    const int tid  = threadIdx.x;
    const int lane = tid & 63;
    const int wv   = tid >> 6;
    const int p    = lane & 15;
    const int cc   = lane >> 4;
    const int pl   = blockIdx.x >> 2;
    const int r0   = (blockIdx.x & 3) * STRIP;

    const float* __restrict__ xin = x + (size_t)pl * 4096;

    // ---- per-lane A-fragments (once) ----
    const int nc = (p < 8) ? p : (p - 8);
    u32x4 Au[3];
    {
        auto packw = [&](int tap) -> u32x4 {
            const float scs = ss[nc * 9 + tap];
            float w[8];
            #pragma unroll
            for (int g = 0; g < 8; ++g) w[g] = sw[(nc * 9 + tap) * 8 + g] * scs;
            u32x4 r;
            r[0] = pkf16(w[0], w[1]); r[1] = pkf16(w[2], w[3]);
            r[2] = pkf16(w[4], w[5]); r[3] = pkf16(w[6], w[7]);
            return r;
        };
        Au[0] = packw(cc);
        Au[1] = packw(4 + cc);
        u32x4 a2 = {0u, 0u, 0u, 0u};
        if (cc == 0) a2 = packw(8);
        else if (cc == 1) {
            a2[0] = pkf16(bw[nc * 9 + 0], bw[nc * 9 + 1]);
            a2[1] = pkf16(bw[nc * 9 + 2], bw[nc * 9 + 3]);
            a2[2] = pkf16(bw[nc * 9 + 4], bw[nc * 9 + 5]);
            a2[3] = pkf16(bw[nc * 9 + 6], bw[nc * 9 + 7]);
        } else if (cc == 2) {
            a2[0] = pkf16(bw[nc * 9 + 8], 0.f);
        }
        Au[2] = a2;
    }

    // ---- P1: site staging (shift-placement basis record) ----
    for (int q = tid; q < SR * SC; q += 256) {
        const int y  = q / SC;
        const int xx = q - y * SC;
        const int gy = r0 + y - 1, gx = xx - 1;
        const bool inb = ((unsigned)gy < 64u) & ((unsigned)gx < 64u);
        const float v = inb ? xin[gy * 64 + gx] : 0.f;

        const float s = __fdividef(v, 1.f + __expf(-v));

        float u  = (v + 2.2f) * 2.5f;
        float mf = floorf(u);
        float t  = u - mf;
        int   m  = (int)mf;
        const bool inr = (m >= 0) && (m <= 10);
        float t2 = t * t, t3 = t2 * t, omt = 1.f - t;
        const float c6 = 1.f / 6.f;
        float wr0 = c6 * omt * omt * omt;
        float wr1 = c6 * (3.f * t3 - 6.f * t2 + 4.f);
        float wr2 = c6 * (-3.f * t3 + 3.f * t2 + 3.f * t + 1.f);
        float wr3 = c6 * t3;
        if (!inr) { wr0 = 0.f; wr1 = 0.f; wr2 = 0.f; wr3 = 0.f; }

        // W = (wr0,wr1,wr2,wr3) as 4 f16 in a u64; rec = W << 16*(m-3) in 128b.
        const unsigned long long W =
            ((unsigned long long)pkf16(wr2, wr3) << 32) | (unsigned long long)pkf16(wr0, wr1);
        const int sh = (m - 3) * 16;
        unsigned long long lo, hi;
        if (sh < 0) {
            lo = W >> (-sh); hi = 0ull;           // W==0 when shift OOR (inr false)
        } else {
            const int t6 = sh & 63;
            const unsigned long long A = W << t6;
            const unsigned long long B = t6 ? (W >> (64 - t6)) : 0ull;
            if (sh < 64) { lo = A; hi = B; }
            else         { lo = 0ull; hi = A; }
        }
        u32x4 rec;
        rec[0] = (unsigned)lo; rec[1] = (unsigned)(lo >> 32);
        rec[2] = (unsigned)hi; rec[3] = (unsigned)(hi >> 32);
        *(u32x4*)&BSb[(y * SC + xx) * 4] = rec;
        Sil[y * SC + xx] = s;
    }
    __syncthreads();

    // ---- P3: MFMA over 16 tiles per wave (colb = wv, orow = 0..15) ----
    float* __restrict__ obase = out + (size_t)pl * (8 * 4096);
    const int px = wv * 16 + p;
    const int t0i = cc / 3,       t0j = cc % 3;
    const int t1i = (4 + cc) / 3, t1j = (4 + cc) % 3;

    for (int orow = 0; orow < STRIP; ++orow) {
        const u32x4 b0 = *(const u32x4*)&BSb[((orow + t0i) * SC + px + t0j) * 4];
        const u32x4 b1 = *(const u32x4*)&BSb[((orow + t1i) * SC + px + t1j) * 4];

        u32x4 b2 = {0u, 0u, 0u, 0u};
        if (cc == 0) {
            b2 = *(const u32x4*)&BSb[((orow + 2) * SC + px + 2) * 4];
        } else if (cc == 1) {
            // inline im2col of silu taps 0..7 (was P2's IC0)
            const float* s0 = &Sil[(orow + 0) * SC + px];
            const float* s1 = &Sil[(orow + 1) * SC + px];
            const float* s2 = &Sil[(orow + 2) * SC + px];
            b2[0] = pkf16(s0[0], s0[1]);
            b2[1] = pkf16(s0[2], s1[0]);
            b2[2] = pkf16(s1[1], s1[2]);
            b2[3] = pkf16(s2[0], s2[1]);
        } else if (cc == 2) {
            b2[0] = pkf16(Sil[(orow + 2) * SC + px + 2], 0.f);
        }

        f32x4 acc = {0.f, 0.f, 0.f, 0.f};
        acc = __builtin_amdgcn_mfma_f32_16x16x32_f16(
            __builtin_bit_cast(h8, Au[0]), __builtin_bit_cast(h8, b0), acc, 0, 0, 0);
        acc = __builtin_amdgcn_mfma_f32_16x16x32_f16(
            __builtin_bit_cast(h8, Au[1]), __builtin_bit_cast(h8, b1), acc, 0, 0, 0);
        acc = __builtin_amdgcn_mfma_f32_16x16x32_f16(
            __builtin_bit_cast(h8, Au[2]), __builtin_bit_cast(h8, b2), acc, 0, 0, 0);

        if (cc < 2) {
            float* o = obase + (size_t)(r0 + orow) * 64 + px;
            #pragma unroll
            for (int r = 0; r < 4; ++r)
                o[(cc * 4 + r) * 4096] = acc[r];
        }
    }
}

extern "C" void kernel_launch(void* const* d_in, const int* in_sizes, int n_in,
                              void* d_out, int out_size, void* d_ws, size_t ws_size,
                              hipStream_t stream) {
    const float* x  = (const float*)d_in[0];
    const float* bw = (const float*)d_in[1];
    const float* sw = (const float*)d_in[2];
    const float* ss = (const float*)d_in[3];
    float* out = (float*)d_out;

    dim3 block(256, 1, 1);
    dim3 grid(1024, 1, 1);   // 256 planes x 4 strips of 16 rows
    hipLaunchKernelGGL(kan_conv_kernel, grid, block, 0, stream, x, bw, sw, ss, out);
}

// Round 17
// 18.667 us; speedup vs baseline: 1.0505x; 1.0505x over previous
//
#include <hip/hip_runtime.h>

typedef float    f32x4 __attribute__((ext_vector_type(4)));
typedef _Float16 h8    __attribute__((ext_vector_type(8)));
typedef unsigned u32x4 __attribute__((ext_vector_type(4)));

#define STRIP 16
#define SR 18          // site rows (strip + halo)
#define SC 66          // site cols (= stride)

__device__ __forceinline__ unsigned pkf16(float a, float b) {
    return __builtin_bit_cast(unsigned, __builtin_amdgcn_cvt_pkrtz(a, b));
}

// Block = 16-row strip of one (b,c) plane; 4 waves; LDS 36.6 KB -> 4 blocks/CU,
// grid 1024 = one residency round (R15 structure).
// P1: basis record via 128-bit shift placement. P2a/2b: im2col silu vecs
// overlaid on dead Sil region. P3: MFMA 16x16x32_f16 with SWAPPED operands
// (A = features row=pixel, B = weights col=n; fragment layouts symmetric,
// HW-verified R9) so C row=pixel, col=n -> lane holds 4 consecutive pixels
// of one n-plane -> single global_store_dwordx4 epilogue.
__global__ __launch_bounds__(256, 4) void kan_conv_kernel(
    const float* __restrict__ x,     // (256, 64, 64)
    const float* __restrict__ bw,    // (8, 9)
    const float* __restrict__ sw,    // (8, 9, 8)
    const float* __restrict__ ss,    // (8, 9)
    float* __restrict__ out)         // (256, 8, 64, 64)
{
    __shared__ __align__(16) unsigned BSb[SR * SC * 4];   // 19,008 B
    __shared__ __align__(16) unsigned UN[4608];           // 18,432 B (Sil | IC0+IC1)

    float*          Sil = (float*)UN;
    unsigned*       IC0 = UN;
    unsigned short* IC1 = (unsigned short*)(UN + 4096);

    const int tid  = threadIdx.x;
    const int lane = tid & 63;
    const int wv   = tid >> 6;
    const int p    = lane & 15;     // pixel (A row) AND weight col n (B)
    const int cc   = lane >> 4;     // k-chunk / C row-block (pixel group)
    const int pl   = blockIdx.x >> 2;
    const int r0   = (blockIdx.x & 3) * STRIP;

    const float* __restrict__ xin = x + (size_t)pl * 4096;

    // ---- per-lane weight fragments (B operand: col = p, k-chunk = cc) ----
    const int nc = (p < 8) ? p : (p - 8);
    u32x4 Au[3];
    {
        auto packw = [&](int tap) -> u32x4 {
            const float scs = ss[nc * 9 + tap];
            float w[8];
            #pragma unroll
            for (int g = 0; g < 8; ++g) w[g] = sw[(nc * 9 + tap) * 8 + g] * scs;
            u32x4 r;
            r[0] = pkf16(w[0], w[1]); r[1] = pkf16(w[2], w[3]);
            r[2] = pkf16(w[4], w[5]); r[3] = pkf16(w[6], w[7]);
            return r;
        };
        Au[0] = packw(cc);
        Au[1] = packw(4 + cc);
        u32x4 a2 = {0u, 0u, 0u, 0u};
        if (cc == 0) a2 = packw(8);
        else if (cc == 1) {
            a2[0] = pkf16(bw[nc * 9 + 0], bw[nc * 9 + 1]);
            a2[1] = pkf16(bw[nc * 9 + 2], bw[nc * 9 + 3]);
            a2[2] = pkf16(bw[nc * 9 + 4], bw[nc * 9 + 5]);
            a2[3] = pkf16(bw[nc * 9 + 6], bw[nc * 9 + 7]);
        } else if (cc == 2) {
            a2[0] = pkf16(bw[nc * 9 + 8], 0.f);
        }
        Au[2] = a2;
    }

    // ---- P1: site staging (shift-placement basis record) ----
    for (int q = tid; q < SR * SC; q += 256) {
        const int y  = q / SC;
        const int xx = q - y * SC;
        const int gy = r0 + y - 1, gx = xx - 1;
        const bool inb = ((unsigned)gy < 64u) & ((unsigned)gx < 64u);
        const float v = inb ? xin[gy * 64 + gx] : 0.f;

        const float s = __fdividef(v, 1.f + __expf(-v));

        float u  = (v + 2.2f) * 2.5f;
        float mf = floorf(u);
        float t  = u - mf;
        int   m  = (int)mf;
        const bool inr = (m >= 0) && (m <= 10);
        float t2 = t * t, t3 = t2 * t, omt = 1.f - t;
        const float c6 = 1.f / 6.f;
        float wr0 = c6 * omt * omt * omt;
        float wr1 = c6 * (3.f * t3 - 6.f * t2 + 4.f);
        float wr2 = c6 * (-3.f * t3 + 3.f * t2 + 3.f * t + 1.f);
        float wr3 = c6 * t3;
        if (!inr) { wr0 = 0.f; wr1 = 0.f; wr2 = 0.f; wr3 = 0.f; }

        const unsigned long long W =
            ((unsigned long long)pkf16(wr2, wr3) << 32) | (unsigned long long)pkf16(wr0, wr1);
        const int sh = (m - 3) * 16;
        unsigned long long lo, hi;
        if (sh < 0) {
            lo = W >> (-sh); hi = 0ull;
        } else {
            const int t6 = sh & 63;
            const unsigned long long A = W << t6;
            const unsigned long long B = t6 ? (W >> (64 - t6)) : 0ull;
            if (sh < 64) { lo = A; hi = B; }
            else         { lo = 0ull; hi = A; }
        }
        u32x4 rec;
        rec[0] = (unsigned)lo; rec[1] = (unsigned)(lo >> 32);
        rec[2] = (unsigned)hi; rec[3] = (unsigned)(hi >> 32);
        *(u32x4*)&BSb[(y * SC + xx) * 4] = rec;
        Sil[y * SC + xx] = s;
    }
    __syncthreads();

    // ---- P2a: im2col silu into registers (static 4 iters; 1024 px) ----
    u32x4    icr[4];
    unsigned ic1r[4];
    #pragma unroll
    for (int it = 0; it < 4; ++it) {
        const int q = tid + it * 256;
        const int r = q >> 6, c = q & 63;
        float s9[9];
        #pragma unroll
        for (int dr = 0; dr < 3; ++dr)
            #pragma unroll
            for (int dc = 0; dc < 3; ++dc)
                s9[dr * 3 + dc] = Sil[(r + dr) * SC + (c + dc)];
        u32x4 ic;
        ic[0] = pkf16(s9[0], s9[1]); ic[1] = pkf16(s9[2], s9[3]);
        ic[2] = pkf16(s9[4], s9[5]); ic[3] = pkf16(s9[6], s9[7]);
        icr[it]  = ic;
        ic1r[it] = pkf16(s9[8], 0.f);
    }
    __syncthreads();

    // ---- P2b: write IC0/IC1 over the dead Sil region ----
    #pragma unroll
    for (int it = 0; it < 4; ++it) {
        const int q = tid + it * 256;
        *(u32x4*)&IC0[q * 4] = icr[it];
        IC1[q] = (unsigned short)(ic1r[it] & 0xFFFFu);
    }
    __syncthreads();

    // ---- P3: MFMA (A = features, B = weights), float4 store epilogue ----
    float* __restrict__ obase = out + (size_t)pl * (8 * 4096);
    const int px = wv * 16 + p;
    const int t0i = cc / 3,       t0j = cc % 3;
    const int t1i = (4 + cc) / 3, t1j = (4 + cc) % 3;

    for (int orow = 0; orow < STRIP; ++orow) {
        const u32x4 b0 = *(const u32x4*)&BSb[((orow + t0i) * SC + px + t0j) * 4];
        const u32x4 b1 = *(const u32x4*)&BSb[((orow + t1i) * SC + px + t1j) * 4];

        u32x4 b2 = {0u, 0u, 0u, 0u};
        if (cc == 0)      b2 = *(const u32x4*)&BSb[((orow + 2) * SC + px + 2) * 4];
        else if (cc == 1) b2 = *(const u32x4*)&IC0[(orow * 64 + px) * 4];
        else if (cc == 2) b2[0] = (unsigned)IC1[orow * 64 + px];

        f32x4 acc = {0.f, 0.f, 0.f, 0.f};
        acc = __builtin_amdgcn_mfma_f32_16x16x32_f16(
            __builtin_bit_cast(h8, b0), __builtin_bit_cast(h8, Au[0]), acc, 0, 0, 0);
        acc = __builtin_amdgcn_mfma_f32_16x16x32_f16(
            __builtin_bit_cast(h8, b1), __builtin_bit_cast(h8, Au[1]), acc, 0, 0, 0);
        acc = __builtin_amdgcn_mfma_f32_16x16x32_f16(
            __builtin_bit_cast(h8, b2), __builtin_bit_cast(h8, Au[2]), acc, 0, 0, 0);

        // C row = pixel (cc*4 + r), col = n (p); store 4 consecutive pixels.
        if (p < 8) {
            float* o = obase + (size_t)p * 4096 + (size_t)(r0 + orow) * 64
                     + wv * 16 + cc * 4;
            *(f32x4*)o = acc;
        }
    }
}

extern "C" void kernel_launch(void* const* d_in, const int* in_sizes, int n_in,
                              void* d_out, int out_size, void* d_ws, size_t ws_size,
                              hipStream_t stream) {
    const float* x  = (const float*)d_in[0];
    const float* bw = (const float*)d_in[1];
    const float* sw = (const float*)d_in[2];
    const float* ss = (const float*)d_in[3];
    float* out = (float*)d_out;

    dim3 block(256, 1, 1);
    dim3 grid(1024, 1, 1);   // 256 planes x 4 strips of 16 rows
    hipLaunchKernelGGL(kan_conv_kernel, grid, block, 0, stream, x, bw, sw, ss, out);
}